// Round 13
// baseline (319.368 us; speedup 1.0000x reference)
//
#include <hip/hip_runtime.h>

typedef __attribute__((ext_vector_type(8))) short short8;
typedef __attribute__((ext_vector_type(16))) float f32x16;

#if __has_builtin(__builtin_amdgcn_exp2f)
#define EXP2(x) __builtin_amdgcn_exp2f(x)
#else
#define EXP2(x) exp2f(x)
#endif

static __device__ __forceinline__ unsigned short f2bf(float f){
  unsigned u = __float_as_uint(f);
  unsigned r = u + 0x7fffu + ((u >> 16) & 1u);
  return (unsigned short)(r >> 16);
}
static __device__ __forceinline__ float bf2f(unsigned short h){
  return __uint_as_float(((unsigned)h) << 16);
}

// ---------------- weight prep: fragment-order split layouts ----------------
// frag-order: idx = ((k>>3)*NC + c)*8 + (k&7)  -> wave B-frag loads are coalesced
__global__ void wprep(const float* __restrict__ Wpre, const float* __restrict__ W1,
                      const float* __restrict__ W2, const float* __restrict__ bl,
                      const float* __restrict__ br,
                      unsigned short* __restrict__ PhiF, unsigned short* __restrict__ PloF,
                      unsigned short* __restrict__ W1hiF, unsigned short* __restrict__ W1loF,
                      unsigned short* __restrict__ W2hiF, unsigned short* __restrict__ W2loF,
                      float* __restrict__ bcat){
  int i = blockIdx.x*256 + threadIdx.x;
  float v; unsigned short* hp; unsigned short* lp; size_t idx;
  if (i < 16384){
    int k = i >> 7, c = i & 127;
    v = Wpre[i]; hp = PhiF; lp = PloF;
    idx = ((size_t)(k>>3)*128 + c)*8 + (k&7);
  } else if (i < 32768){
    int j = i - 16384; int k = j >> 7, c = j & 127;
    v = W1[j]; hp = W1hiF; lp = W1loF;
    idx = ((size_t)(k>>3)*128 + c)*8 + (k&7);
  } else if (i < 37888){
    int j = i - 32768; int k = j / 40, c = j % 40;
    v = W2[j]; hp = W2hiF; lp = W2loF;
    idx = ((size_t)(k>>3)*40 + c)*8 + (k&7);
  } else if (i < 38144){
    int j = i - 37888;
    bcat[j] = (j < 128) ? bl[j] : br[j-128];
    return;
  } else return;
  unsigned short h = f2bf(v);
  hp[idx] = h;
  lp[idx] = f2bf(v - bf2f(h));
}

// Wcomb = Wpre @ [Wl|Wr]  (128x256 fp32), written frag-order split (NC=256)
__global__ __launch_bounds__(256) void wcomb_kernel(
    const float* __restrict__ Wpre, const float* __restrict__ Wl,
    const float* __restrict__ Wr,
    unsigned short* __restrict__ ChiF, unsigned short* __restrict__ CloF){
  int tid = blockIdx.x*256 + threadIdx.x;     // 32768 = 128 rows x 256 cols
  int r = tid >> 8;                           // k-index of B operand
  int c = tid & 255;
  const float* B = (c < 128) ? (Wl + c) : (Wr + (c - 128));
  float s = 0.f;
  for (int k = 0; k < 128; ++k)
    s = fmaf(Wpre[r*128 + k], B[(size_t)k*128], s);
  unsigned short h = f2bf(s);
  size_t idx = ((size_t)(r>>3)*256 + c)*8 + (r&7);
  ChiF[idx] = h;
  CloF[idx] = f2bf(s - bf2f(h));
}

// ---------------- histogram + rank + mean in one pass ----------------
__global__ void count_mean(const int* __restrict__ ei, const float* __restrict__ ew,
                           int* __restrict__ deg, int* __restrict__ rk,
                           float* __restrict__ msum, int E){
  float s = 0.f;
  for (int e = blockIdx.x*256 + threadIdx.x; e < E; e += gridDim.x*256){
    rk[e] = atomicAdd(&deg[ei[E + e]], 1);
    s += ew[e];
  }
  for (int d = 32; d > 0; d >>= 1) s += __shfl_down(s, d, 64);
  __shared__ float ps[4];
  int lane = threadIdx.x & 63, w = threadIdx.x >> 6;
  if (lane == 0) ps[w] = s;
  __syncthreads();
  if (threadIdx.x == 0) atomicAdd(msum, (ps[0]+ps[1]+ps[2]+ps[3]) / (float)E);
}

// ---------------- scans (+ LDS-aggregated degree histogram / perm) ----------------
__global__ __launch_bounds__(256) void scan1_kernel(const int* __restrict__ deg, int* __restrict__ rowptr,
                                                    int* __restrict__ bsum, int* __restrict__ dhist, int N){
  __shared__ int s[256];
  __shared__ int lhist[256];
  int i = blockIdx.x*256 + threadIdx.x;
  lhist[threadIdx.x] = 0;
  __syncthreads();
  int v = (i < N) ? deg[i] : 0;
  if (i < N) atomicAdd(&lhist[v < 255 ? v : 255], 1);
  s[threadIdx.x] = v;
  __syncthreads();
  for (int off = 1; off < 256; off <<= 1){
    int t = (threadIdx.x >= off) ? s[threadIdx.x - off] : 0;
    __syncthreads();
    s[threadIdx.x] += t;
    __syncthreads();
  }
  if (i < N) rowptr[i + 1] = s[threadIdx.x];
  if (threadIdx.x == 255) bsum[blockIdx.x] = s[255];
  int c = lhist[threadIdx.x];
  if (c > 0) atomicAdd(&dhist[threadIdx.x], c);
}

__global__ __launch_bounds__(512) void scan2_kernel(const int* __restrict__ bsum, int* __restrict__ boff, int nb,
                                                    const int* __restrict__ dhist, int* __restrict__ dhoff){
  __shared__ int s[512];
  __shared__ int s2[256];
  int v = (threadIdx.x < nb) ? bsum[threadIdx.x] : 0;
  s[threadIdx.x] = v;
  __syncthreads();
  for (int off = 1; off < 512; off <<= 1){
    int t = (threadIdx.x >= off) ? s[threadIdx.x - off] : 0;
    __syncthreads();
    s[threadIdx.x] += t;
    __syncthreads();
  }
  if (threadIdx.x < nb) boff[threadIdx.x] = s[threadIdx.x] - v;
  int v2 = 0;
  if (threadIdx.x < 256){ v2 = dhist[threadIdx.x]; s2[threadIdx.x] = v2; }
  __syncthreads();
  for (int off = 1; off < 256; off <<= 1){
    int t = 0;
    if (threadIdx.x < 256 && threadIdx.x >= off) t = s2[threadIdx.x - off];
    __syncthreads();
    if (threadIdx.x < 256) s2[threadIdx.x] += t;
    __syncthreads();
  }
  if (threadIdx.x < 256) dhoff[threadIdx.x] = s2[threadIdx.x] - v2;
}

__global__ __launch_bounds__(256) void scan3_kernel(int* __restrict__ rowptr, const int* __restrict__ boff,
                                                    const int* __restrict__ deg, int* __restrict__ dhoff,
                                                    int* __restrict__ perm, int N){
  __shared__ int lcnt[256];
  __shared__ int lbase[256];
  int i = blockIdx.x*256 + threadIdx.x;
  lcnt[threadIdx.x] = 0;
  __syncthreads();
  if (i == 0) rowptr[0] = 0;
  int d = 0, lr = 0;
  if (i < N){
    rowptr[i + 1] += boff[i >> 8];
    d = deg[i]; d = d < 255 ? d : 255;
    lr = atomicAdd(&lcnt[d], 1);
  }
  __syncthreads();
  int c = lcnt[threadIdx.x];
  if (c > 0) lbase[threadIdx.x] = atomicAdd(&dhoff[threadIdx.x], c);
  __syncthreads();
  if (i < N) perm[lbase[d] + lr] = i;
}

// rank-based scatter: no atomics
__global__ void fill_kernel(const int* __restrict__ ei, const float* __restrict__ ew,
                            const int* __restrict__ rowptr, const int* __restrict__ rk,
                            int2* __restrict__ erec, int E){
  int e = blockIdx.x*256 + threadIdx.x;
  if (e >= E) return;
  int dst = ei[E + e];
  erec[rowptr[dst] + rk[e]] = make_int2(ei[e], __float_as_int(ew[e]));
}

// ---------------- stage A tile (64x128 fp32 -> split bf16 LDS) ----------------
template<int NT>
static __device__ __forceinline__ void stageA(short* alds, const float* __restrict__ A,
                                              int row0, int N, int t){
  for (int g = t; g < 1024; g += NT){
    int r = g >> 4, k8 = g & 15;
    int grow = row0 + r;
    float4 p0, p1;
    if (grow < N){
      const float* ap = A + (size_t)grow*128 + k8*8;
      p0 = *(const float4*)ap;
      p1 = *(const float4*)(ap + 4);
    } else {
      p0 = make_float4(0.f,0.f,0.f,0.f); p1 = p0;
    }
    float vv[8] = {p0.x,p0.y,p0.z,p0.w,p1.x,p1.y,p1.z,p1.w};
    short8 hv, lv;
    #pragma unroll
    for (int j = 0; j < 8; ++j){
      unsigned short h = f2bf(vv[j]);
      hv[j] = (short)h;
      lv[j] = (short)f2bf(vv[j] - bf2f(h));
    }
    int slot = k8 ^ (r & 15);
    *(short8*)&alds[r*128 + slot*8] = hv;
    *(short8*)&alds[8192 + r*128 + slot*8] = lv;
  }
}

// 3-pass MFMA over two 32-row tiles, A from LDS, B frags in regs
#define MFMA_KLOOP(ACC0, ACC1) \
  _Pragma("unroll") \
  for (int ks = 0; ks < 8; ++ks){ \
    int k8 = ks*2 + kg; \
    const short* a0 = &alds[r0*128 + (k8 ^ sx)*8]; \
    const short* a1 = &alds[(r0+32)*128 + (k8 ^ sx)*8]; \
    short8 a0h = *(const short8*)a0; \
    short8 a0l = *(const short8*)(a0 + 8192); \
    short8 a1h = *(const short8*)a1; \
    short8 a1l = *(const short8*)(a1 + 8192); \
    ACC0 = __builtin_amdgcn_mfma_f32_32x32x16_bf16(a0h, bh[ks],  ACC0, 0,0,0); \
    ACC1 = __builtin_amdgcn_mfma_f32_32x32x16_bf16(a1h, bh[ks],  ACC1, 0,0,0); \
    ACC0 = __builtin_amdgcn_mfma_f32_32x32x16_bf16(a0l, bh[ks],  ACC0, 0,0,0); \
    ACC1 = __builtin_amdgcn_mfma_f32_32x32x16_bf16(a1l, bh[ks],  ACC1, 0,0,0); \
    ACC0 = __builtin_amdgcn_mfma_f32_32x32x16_bf16(a0h, bl8[ks], ACC0, 0,0,0); \
    ACC1 = __builtin_amdgcn_mfma_f32_32x32x16_bf16(a1h, bl8[ks], ACC1, 0,0,0); \
  }

// ---------------- fused pre (single-phase): hout = x@Wpre ; xlr = x@Wcomb + bcat ----------------
// 12 waves: strips 0-3 -> Wpre cols (hout fp32), strips 4-11 -> Wcomb cols (xlr bf16)
__global__ __launch_bounds__(768) void pre_kernel(
    const float* __restrict__ A,
    const unsigned short* __restrict__ PhiF, const unsigned short* __restrict__ PloF,
    const unsigned short* __restrict__ ChiF, const unsigned short* __restrict__ CloF,
    const float* __restrict__ bcat,
    float* __restrict__ hout, unsigned short* __restrict__ xlr, int N)
{
  __shared__ short alds[2*64*128];
  const int t = threadIdx.x;
  const int row0 = blockIdx.x * 64;
  const int lane = t & 63, w = t >> 6;
  const int cl = lane & 31, kg = lane >> 5;
  const int sx = cl & 15;
  const int S = w * 32;                 // strip base within 384 cols
  const bool isP = S < 128;
  const int col = isP ? (S + cl) : (S - 128 + cl);
  const int NC  = isP ? 128 : 256;
  const unsigned short* Bhi = isP ? PhiF : ChiF;
  const unsigned short* Blo = isP ? PloF : CloF;

  // coalesced frag-order B loads (independent of LDS stage)
  short8 bh[8], bl8[8];
  #pragma unroll
  for (int ks = 0; ks < 8; ++ks){
    size_t off = ((size_t)(ks*2 + kg)*NC + col)*8;
    bh[ks]  = *(const short8*)(Bhi + off);
    bl8[ks] = *(const short8*)(Blo + off);
  }

  stageA<768>(alds, A, row0, N, t);
  __syncthreads();

  f32x16 acc0, acc1;
  #pragma unroll
  for (int i = 0; i < 16; ++i){ acc0[i] = 0.f; acc1[i] = 0.f; }
  const int r0 = cl;
  MFMA_KLOOP(acc0, acc1)

  if (isP){
    #pragma unroll
    for (int rt2 = 0; rt2 < 2; ++rt2){
      const f32x16& ac = rt2 ? acc1 : acc0;
      #pragma unroll
      for (int reg = 0; reg < 16; ++reg){
        int row = rt2*32 + (reg & 3) + 8*(reg >> 2) + 4*kg;
        int grow = row0 + row;
        if (grow < N) hout[(size_t)grow*128 + col] = ac[reg];
      }
    }
  } else {
    float bv = bcat[col];
    #pragma unroll
    for (int rt2 = 0; rt2 < 2; ++rt2){
      const f32x16& ac = rt2 ? acc1 : acc0;
      #pragma unroll
      for (int reg = 0; reg < 16; ++reg){
        int row = rt2*32 + (reg & 3) + 8*(reg >> 2) + 4*kg;
        int grow = row0 + row;
        if (grow < N) xlr[(size_t)grow*256 + col] = f2bf(ac[reg] + bv);
      }
    }
  }
}

// ---------------- fused MLP: logits = relu(h@W1+b1)@W2 + b2 ----------------
__global__ __launch_bounds__(256) void mlp_kernel(
    const float* __restrict__ A,
    const unsigned short* __restrict__ B1hi, const unsigned short* __restrict__ B1lo,
    const float* __restrict__ b1,
    const unsigned short* __restrict__ B2hi, const unsigned short* __restrict__ B2lo,
    const float* __restrict__ b2,
    float* __restrict__ logits, int N)
{
  __shared__ short alds[2*64*128];
  const int t = threadIdx.x;
  const int row0 = blockIdx.x * 64;
  stageA<256>(alds, A, row0, N, t);
  __syncthreads();

  const int lane = t & 63, w = t >> 6;
  const int cl = lane & 31, kg = lane >> 5;
  const int r0 = cl;
  const int sx = r0 & 15;

  {
    const int col = w*32 + cl;
    short8 bh[8], bl8[8];
    #pragma unroll
    for (int ks = 0; ks < 8; ++ks){
      size_t off = ((size_t)(ks*2 + kg)*128 + col)*8;   // frag-order, coalesced
      bh[ks]  = *(const short8*)(B1hi + off);
      bl8[ks] = *(const short8*)(B1lo + off);
    }
    f32x16 acc0, acc1;
    #pragma unroll
    for (int i = 0; i < 16; ++i){ acc0[i] = 0.f; acc1[i] = 0.f; }
    MFMA_KLOOP(acc0, acc1)

    float bv = b1[col];
    __syncthreads();
    #pragma unroll
    for (int rt = 0; rt < 2; ++rt){
      const f32x16& ac = rt ? acc1 : acc0;
      #pragma unroll
      for (int reg = 0; reg < 16; ++reg){
        int row = rt*32 + (reg & 3) + 8*(reg >> 2) + 4*kg;
        float v = fmaxf(ac[reg] + bv, 0.f);
        unsigned short h = f2bf(v);
        unsigned short l = f2bf(v - bf2f(h));
        int idx = row*128 + (((col >> 3) ^ (row & 15)) << 3) + (col & 7);
        alds[idx] = (short)h;
        alds[8192 + idx] = (short)l;
      }
    }
    __syncthreads();
  }

  if (w < 2){
    const int col = w*32 + cl;
    const bool cok = col < 40;
    short8 bh[8], bl8[8];
    #pragma unroll
    for (int ks = 0; ks < 8; ++ks){
      if (cok){
        size_t off = ((size_t)(ks*2 + kg)*40 + col)*8;  // frag-order, NC=40
        bh[ks]  = *(const short8*)(B2hi + off);
        bl8[ks] = *(const short8*)(B2lo + off);
      } else {
        #pragma unroll
        for (int j = 0; j < 8; ++j){ bh[ks][j] = 0; bl8[ks][j] = 0; }
      }
    }
    f32x16 acc0, acc1;
    #pragma unroll
    for (int i = 0; i < 16; ++i){ acc0[i] = 0.f; acc1[i] = 0.f; }
    MFMA_KLOOP(acc0, acc1)

    if (cok){
      float bv = b2[col];
      #pragma unroll
      for (int rt = 0; rt < 2; ++rt){
        const f32x16& ac = rt ? acc1 : acc0;
        #pragma unroll
        for (int reg = 0; reg < 16; ++reg){
          int row = rt*32 + (reg & 3) + 8*(reg >> 2) + 4*kg;
          int grow = row0 + row;
          if (grow < N) logits[(size_t)grow*40 + col] = ac[reg] + bv;
        }
      }
    }
  }
}

// ---------------- gather: 4 degree-matched nodes/wave, unroll-2 + depth-3 pipeline ----------------
__global__ __launch_bounds__(256) void gather_kernel(
    const int* __restrict__ rowptr, const int2* __restrict__ erec,
    const unsigned short* __restrict__ xlr,     // [N][256] bf16: xl | xr
    const int* __restrict__ perm,
    const float* __restrict__ We, const float* __restrict__ att,
    const float* __restrict__ msum, const float* __restrict__ bgat,
    float* __restrict__ hbuf, int N)
{
  const int wid  = threadIdx.x >> 6;
  const int lane = threadIdx.x & 63;
  const int g    = lane >> 4;
  const int l    = lane & 15;
  const int ch0  = l * 8;
  const int slot = (blockIdx.x*4 + wid)*4 + g;
  const bool nok = slot < N;
  const int n    = nok ? perm[slot] : 0;

  float xrv[8], wev[8], at6[8], at4[8];
  {
    short8 q = *(const short8*)&xlr[(size_t)n*256 + 128 + ch0];
    float4 w0 = *(const float4*)&We[ch0];
    float4 w1 = *(const float4*)&We[ch0+4];
    float4 a0 = *(const float4*)&att[ch0];
    float4 a1 = *(const float4*)&att[ch0+4];
    const float L2E = 1.4426950408889634f;
    float wv[8] = {w0.x,w0.y,w0.z,w0.w,w1.x,w1.y,w1.z,w1.w};
    float av[8] = {a0.x,a0.y,a0.z,a0.w,a1.x,a1.y,a1.z,a1.w};
    #pragma unroll
    for (int j = 0; j < 8; ++j){
      xrv[j] = bf2f((unsigned short)q[j]);
      wev[j] = wv[j];
      at6[j] = av[j]*0.6f*L2E;    // lrelu(z) = 0.6z + 0.4|z|, fold log2(e)
      at4[j] = av[j]*0.4f*L2E;
    }
  }

  float num[8];
  #pragma unroll
  for (int j = 0; j < 8; ++j) num[j] = 0.f;
  float den = 0.f;

  const float wm = msum[0];
  int beg = 0, end = 0;
  if (nok){ beg = rowptr[n]; end = rowptr[n + 1]; }
  const int cnt = nok ? (end - beg + 1) : 0;

  int itMax = cnt;
  itMax = max(itMax, __shfl_xor(itMax, 16, 64));
  itMax = max(itMax, __shfl_xor(itMax, 32, 64));

  const int2 selfrec = make_int2(n, __float_as_int(wm));

  int pos = beg;
  int2 rec0 = (pos     < end) ? erec[pos]     : selfrec;
  int2 rec1 = (pos + 1 < end) ? erec[pos + 1] : selfrec;
  int2 rec2 = (pos + 2 < end) ? erec[pos + 2] : selfrec;
  short8 pv0 = *(const short8*)&xlr[(size_t)rec0.x*256 + ch0];
  short8 pv1 = *(const short8*)&xlr[(size_t)rec1.x*256 + ch0];
  short8 pv2 = *(const short8*)&xlr[(size_t)rec2.x*256 + ch0];

  for (int it = 0; it < itMax; it += 2){
    int2 rec3 = (pos + 3 < end) ? erec[pos + 3] : selfrec;
    int2 rec4 = (pos + 4 < end) ? erec[pos + 4] : selfrec;
    short8 pv3 = *(const short8*)&xlr[(size_t)rec3.x*256 + ch0];
    short8 pv4 = *(const short8*)&xlr[(size_t)rec4.x*256 + ch0];

    {
      const bool act = it < cnt;
      const float wj = __int_as_float(rec0.y);
      float xlv[8];
      #pragma unroll
      for (int q = 0; q < 8; ++q) xlv[q] = bf2f((unsigned short)pv0[q]);
      float p = 0.f;
      #pragma unroll
      for (int q = 0; q < 8; ++q){
        float z = fmaf(wj, wev[q], xlv[q] + xrv[q]);
        p = fmaf(at6[q], z, p);
        p = fmaf(at4[q], fabsf(z), p);
      }
      p += __shfl_xor(p, 1, 64);
      p += __shfl_xor(p, 2, 64);
      float ex = act ? EXP2(p) : 0.f;
      den += ex;
      #pragma unroll
      for (int q = 0; q < 8; ++q) num[q] = fmaf(ex, xlv[q], num[q]);
    }
    {
      const bool act = (it + 1) < cnt;
      const float wj = __int_as_float(rec1.y);
      float xlv[8];
      #pragma unroll
      for (int q = 0; q < 8; ++q) xlv[q] = bf2f((unsigned short)pv1[q]);
      float p = 0.f;
      #pragma unroll
      for (int q = 0; q < 8; ++q){
        float z = fmaf(wj, wev[q], xlv[q] + xrv[q]);
        p = fmaf(at6[q], z, p);
        p = fmaf(at4[q], fabsf(z), p);
      }
      p += __shfl_xor(p, 1, 64);
      p += __shfl_xor(p, 2, 64);
      float ex = act ? EXP2(p) : 0.f;
      den += ex;
      #pragma unroll
      for (int q = 0; q < 8; ++q) num[q] = fmaf(ex, xlv[q], num[q]);
    }

    rec0 = rec2; rec1 = rec3; rec2 = rec4;
    pv0 = pv2;  pv1 = pv3;  pv2 = pv4;
    pos += 2;
  }

  if (nok){
    float inv = 1.f / (den + 1e-16f);
    float o[8];
    #pragma unroll
    for (int j = 0; j < 8; ++j){
      float v = num[j]*inv + bgat[ch0+j];
      o[j] = v > 0.f ? v : expm1f(v);   // ELU
    }
    float4 h0a = *(const float4*)&hbuf[(size_t)n*128 + ch0];
    float4 h0b = *(const float4*)&hbuf[(size_t)n*128 + ch0 + 4];
    h0a.x += o[0]; h0a.y += o[1]; h0a.z += o[2]; h0a.w += o[3];
    h0b.x += o[4]; h0b.y += o[5]; h0b.z += o[6]; h0b.w += o[7];
    *(float4*)&hbuf[(size_t)n*128 + ch0]     = h0a;
    *(float4*)&hbuf[(size_t)n*128 + ch0 + 4] = h0b;
  }
}

extern "C" void kernel_launch(void* const* d_in, const int* in_sizes, int n_in,
                              void* d_out, int out_size, void* d_ws, size_t ws_size,
                              hipStream_t stream)
{
  const float* x    = (const float*)d_in[0];
  const int*   ei   = (const int*)  d_in[1];
  const float* ew   = (const float*)d_in[2];
  const float* Wpre = (const float*)d_in[3];
  const float* Wl   = (const float*)d_in[4];
  const float* bl   = (const float*)d_in[5];
  const float* Wr   = (const float*)d_in[6];
  const float* br   = (const float*)d_in[7];
  const float* We   = (const float*)d_in[8];
  const float* att  = (const float*)d_in[9];
  const float* bgat = (const float*)d_in[10];
  const float* W1   = (const float*)d_in[11];
  const float* b1   = (const float*)d_in[12];
  const float* W2   = (const float*)d_in[13];
  const float* b2   = (const float*)d_in[14];

  const int N = in_sizes[0] / 128;
  const int E = in_sizes[2];
  const int nb = (N + 255) / 256;

  float* hout   = (float*)d_out;               // [N,128]
  float* logits = hout + (size_t)N*128;        // [N,40]

  // workspace layout
  unsigned short* xlr = (unsigned short*)d_ws; // N*256 bf16 (xl | xr per row)
  int2*  erec   = (int2*)(xlr + (size_t)N*256);// E records (src, w)
  int*   rk     = (int*)(erec + E);            // E ranks
  int*   rowptr = rk + E;                      // N+1
  int*   cursor = rowptr + N + 1;              // N (deg)
  float* msum   = (float*)(cursor + N);        // 1
  int*   dhist  = (int*)(msum + 1);            // 256
  int*   bsum   = dhist + 256;                 // nb
  int*   boff   = bsum + nb;                   // nb
  int*   dhoff  = boff + nb;                   // 256
  int*   perm   = dhoff + 256;                 // N
  float* bcat   = (float*)(perm + N);          // 256
  unsigned short* wsp = (unsigned short*)(((uintptr_t)(bcat + 256) + 15) & ~(uintptr_t)15);
  unsigned short* PhiF  = wsp;                 // 128*128
  unsigned short* PloF  = PhiF + 16384;
  unsigned short* ChiF  = PloF + 16384;        // 256*128 (Wcomb)
  unsigned short* CloF  = ChiF + 32768;
  unsigned short* W1hiF = CloF + 32768;        // 128*128
  unsigned short* W1loF = W1hiF + 16384;
  unsigned short* W2hiF = W1loF + 16384;       // 40*128
  unsigned short* W2loF = W2hiF + 5120;

  hipMemsetAsync(cursor, 0, (size_t)(N + 1 + 256) * sizeof(int), stream);

  wprep<<<150, 256, 0, stream>>>(Wpre, W1, W2, bl, br,
                                 PhiF, PloF, W1hiF, W1loF, W2hiF, W2loF, bcat);
  wcomb_kernel<<<128, 256, 0, stream>>>(Wpre, Wl, Wr, ChiF, CloF);
  count_mean<<<1024, 256, 0, stream>>>(ei, ew, cursor, rk, msum, E);
  scan1_kernel<<<nb, 256, 0, stream>>>(cursor, rowptr, bsum, dhist, N);
  scan2_kernel<<<1, 512, 0, stream>>>(bsum, boff, nb, dhist, dhoff);
  scan3_kernel<<<nb, 256, 0, stream>>>(rowptr, boff, cursor, dhoff, perm, N);
  fill_kernel<<<(E + 255)/256, 256, 0, stream>>>(ei, ew, rowptr, rk, erec, E);

  const int gg = (N + 63) / 64;
  pre_kernel<<<gg, 768, 0, stream>>>(x, PhiF, PloF, ChiF, CloF, bcat, hout, xlr, N);

  gather_kernel<<<(N + 15)/16, 256, 0, stream>>>(rowptr, erec, xlr, perm, We, att, msum, bgat, hout, N);

  mlp_kernel<<<gg, 256, 0, stream>>>(hout, W1hiF, W1loF, b1, W2hiF, W2loF, b2, logits, N);
}

// Round 14
// 299.277 us; speedup vs baseline: 1.0671x; 1.0671x over previous
//
#include <hip/hip_runtime.h>

typedef __attribute__((ext_vector_type(8))) short short8;
typedef __attribute__((ext_vector_type(16))) float f32x16;

#if __has_builtin(__builtin_amdgcn_exp2f)
#define EXP2(x) __builtin_amdgcn_exp2f(x)
#else
#define EXP2(x) exp2f(x)
#endif

static __device__ __forceinline__ unsigned short f2bf(float f){
  unsigned u = __float_as_uint(f);
  unsigned r = u + 0x7fffu + ((u >> 16) & 1u);
  return (unsigned short)(r >> 16);
}
static __device__ __forceinline__ float bf2f(unsigned short h){
  return __uint_as_float(((unsigned)h) << 16);
}

// ---------------- weight prep: fragment-order split layouts ----------------
// frag-order: idx = ((k>>3)*NC + c)*8 + (k&7)  -> wave B-frag loads are coalesced
__global__ void wprep(const float* __restrict__ Wpre, const float* __restrict__ W1,
                      const float* __restrict__ W2, const float* __restrict__ bl,
                      const float* __restrict__ br,
                      unsigned short* __restrict__ PhiF, unsigned short* __restrict__ PloF,
                      unsigned short* __restrict__ W1hiF, unsigned short* __restrict__ W1loF,
                      unsigned short* __restrict__ W2hiF, unsigned short* __restrict__ W2loF,
                      float* __restrict__ bcat){
  int i = blockIdx.x*256 + threadIdx.x;
  float v; unsigned short* hp; unsigned short* lp; size_t idx;
  if (i < 16384){
    int k = i >> 7, c = i & 127;
    v = Wpre[i]; hp = PhiF; lp = PloF;
    idx = ((size_t)(k>>3)*128 + c)*8 + (k&7);
  } else if (i < 32768){
    int j = i - 16384; int k = j >> 7, c = j & 127;
    v = W1[j]; hp = W1hiF; lp = W1loF;
    idx = ((size_t)(k>>3)*128 + c)*8 + (k&7);
  } else if (i < 37888){
    int j = i - 32768; int k = j / 40, c = j % 40;
    v = W2[j]; hp = W2hiF; lp = W2loF;
    idx = ((size_t)(k>>3)*40 + c)*8 + (k&7);
  } else if (i < 38144){
    int j = i - 37888;
    bcat[j] = (j < 128) ? bl[j] : br[j-128];
    return;
  } else return;
  unsigned short h = f2bf(v);
  hp[idx] = h;
  lp[idx] = f2bf(v - bf2f(h));
}

// Wcomb = Wpre @ [Wl|Wr]  (128x256 fp32), written frag-order split (NC=256)
__global__ __launch_bounds__(256) void wcomb_kernel(
    const float* __restrict__ Wpre, const float* __restrict__ Wl,
    const float* __restrict__ Wr,
    unsigned short* __restrict__ ChiF, unsigned short* __restrict__ CloF){
  int tid = blockIdx.x*256 + threadIdx.x;     // 32768 = 128 rows x 256 cols
  int r = tid >> 8;
  int c = tid & 255;
  const float* B = (c < 128) ? (Wl + c) : (Wr + (c - 128));
  float s = 0.f;
  for (int k = 0; k < 128; ++k)
    s = fmaf(Wpre[r*128 + k], B[(size_t)k*128], s);
  unsigned short h = f2bf(s);
  size_t idx = ((size_t)(r>>3)*256 + c)*8 + (r&7);
  ChiF[idx] = h;
  CloF[idx] = f2bf(s - bf2f(h));
}

// ---------------- histogram + rank + mean in one pass ----------------
__global__ void count_mean(const int* __restrict__ ei, const float* __restrict__ ew,
                           int* __restrict__ deg, int* __restrict__ rk,
                           float* __restrict__ msum, int E){
  float s = 0.f;
  for (int e = blockIdx.x*256 + threadIdx.x; e < E; e += gridDim.x*256){
    rk[e] = atomicAdd(&deg[ei[E + e]], 1);
    s += ew[e];
  }
  for (int d = 32; d > 0; d >>= 1) s += __shfl_down(s, d, 64);
  __shared__ float ps[4];
  int lane = threadIdx.x & 63, w = threadIdx.x >> 6;
  if (lane == 0) ps[w] = s;
  __syncthreads();
  if (threadIdx.x == 0) atomicAdd(msum, (ps[0]+ps[1]+ps[2]+ps[3]) / (float)E);
}

// ---------------- scans (+ LDS-aggregated degree histogram / perm) ----------------
__global__ __launch_bounds__(256) void scan1_kernel(const int* __restrict__ deg, int* __restrict__ rowptr,
                                                    int* __restrict__ bsum, int* __restrict__ dhist, int N){
  __shared__ int s[256];
  __shared__ int lhist[256];
  int i = blockIdx.x*256 + threadIdx.x;
  lhist[threadIdx.x] = 0;
  __syncthreads();
  int v = (i < N) ? deg[i] : 0;
  if (i < N) atomicAdd(&lhist[v < 255 ? v : 255], 1);
  s[threadIdx.x] = v;
  __syncthreads();
  for (int off = 1; off < 256; off <<= 1){
    int t = (threadIdx.x >= off) ? s[threadIdx.x - off] : 0;
    __syncthreads();
    s[threadIdx.x] += t;
    __syncthreads();
  }
  if (i < N) rowptr[i + 1] = s[threadIdx.x];
  if (threadIdx.x == 255) bsum[blockIdx.x] = s[255];
  int c = lhist[threadIdx.x];
  if (c > 0) atomicAdd(&dhist[threadIdx.x], c);
}

__global__ __launch_bounds__(512) void scan2_kernel(const int* __restrict__ bsum, int* __restrict__ boff, int nb,
                                                    const int* __restrict__ dhist, int* __restrict__ dhoff){
  __shared__ int s[512];
  __shared__ int s2[256];
  int v = (threadIdx.x < nb) ? bsum[threadIdx.x] : 0;
  s[threadIdx.x] = v;
  __syncthreads();
  for (int off = 1; off < 512; off <<= 1){
    int t = (threadIdx.x >= off) ? s[threadIdx.x - off] : 0;
    __syncthreads();
    s[threadIdx.x] += t;
    __syncthreads();
  }
  if (threadIdx.x < nb) boff[threadIdx.x] = s[threadIdx.x] - v;
  int v2 = 0;
  if (threadIdx.x < 256){ v2 = dhist[threadIdx.x]; s2[threadIdx.x] = v2; }
  __syncthreads();
  for (int off = 1; off < 256; off <<= 1){
    int t = 0;
    if (threadIdx.x < 256 && threadIdx.x >= off) t = s2[threadIdx.x - off];
    __syncthreads();
    if (threadIdx.x < 256) s2[threadIdx.x] += t;
    __syncthreads();
  }
  if (threadIdx.x < 256) dhoff[threadIdx.x] = s2[threadIdx.x] - v2;
}

__global__ __launch_bounds__(256) void scan3_kernel(int* __restrict__ rowptr, const int* __restrict__ boff,
                                                    const int* __restrict__ deg, int* __restrict__ dhoff,
                                                    int* __restrict__ perm, int N){
  __shared__ int lcnt[256];
  __shared__ int lbase[256];
  int i = blockIdx.x*256 + threadIdx.x;
  lcnt[threadIdx.x] = 0;
  __syncthreads();
  if (i == 0) rowptr[0] = 0;
  int d = 0, lr = 0;
  if (i < N){
    rowptr[i + 1] += boff[i >> 8];
    d = deg[i]; d = d < 255 ? d : 255;
    lr = atomicAdd(&lcnt[d], 1);
  }
  __syncthreads();
  int c = lcnt[threadIdx.x];
  if (c > 0) lbase[threadIdx.x] = atomicAdd(&dhoff[threadIdx.x], c);
  __syncthreads();
  if (i < N) perm[lbase[d] + lr] = i;
}

// rank-based scatter: no atomics
__global__ void fill_kernel(const int* __restrict__ ei, const float* __restrict__ ew,
                            const int* __restrict__ rowptr, const int* __restrict__ rk,
                            int2* __restrict__ erec, int E){
  int e = blockIdx.x*256 + threadIdx.x;
  if (e >= E) return;
  int dst = ei[E + e];
  erec[rowptr[dst] + rk[e]] = make_int2(ei[e], __float_as_int(ew[e]));
}

// ---------------- stage A tile (64x128 fp32 -> split bf16 LDS) ----------------
template<int NT>
static __device__ __forceinline__ void stageA(short* alds, const float* __restrict__ A,
                                              int row0, int N, int t){
  for (int g = t; g < 1024; g += NT){
    int r = g >> 4, k8 = g & 15;
    int grow = row0 + r;
    float4 p0, p1;
    if (grow < N){
      const float* ap = A + (size_t)grow*128 + k8*8;
      p0 = *(const float4*)ap;
      p1 = *(const float4*)(ap + 4);
    } else {
      p0 = make_float4(0.f,0.f,0.f,0.f); p1 = p0;
    }
    float vv[8] = {p0.x,p0.y,p0.z,p0.w,p1.x,p1.y,p1.z,p1.w};
    short8 hv, lv;
    #pragma unroll
    for (int j = 0; j < 8; ++j){
      unsigned short h = f2bf(vv[j]);
      hv[j] = (short)h;
      lv[j] = (short)f2bf(vv[j] - bf2f(h));
    }
    int slot = k8 ^ (r & 15);
    *(short8*)&alds[r*128 + slot*8] = hv;
    *(short8*)&alds[8192 + r*128 + slot*8] = lv;
  }
}

// 3-pass MFMA over two 32-row tiles, A from LDS, B frags in regs
#define MFMA_KLOOP(ACC0, ACC1) \
  _Pragma("unroll") \
  for (int ks = 0; ks < 8; ++ks){ \
    int k8 = ks*2 + kg; \
    const short* a0 = &alds[r0*128 + (k8 ^ sx)*8]; \
    const short* a1 = &alds[(r0+32)*128 + (k8 ^ sx)*8]; \
    short8 a0h = *(const short8*)a0; \
    short8 a0l = *(const short8*)(a0 + 8192); \
    short8 a1h = *(const short8*)a1; \
    short8 a1l = *(const short8*)(a1 + 8192); \
    ACC0 = __builtin_amdgcn_mfma_f32_32x32x16_bf16(a0h, bh[ks],  ACC0, 0,0,0); \
    ACC1 = __builtin_amdgcn_mfma_f32_32x32x16_bf16(a1h, bh[ks],  ACC1, 0,0,0); \
    ACC0 = __builtin_amdgcn_mfma_f32_32x32x16_bf16(a0l, bh[ks],  ACC0, 0,0,0); \
    ACC1 = __builtin_amdgcn_mfma_f32_32x32x16_bf16(a1l, bh[ks],  ACC1, 0,0,0); \
    ACC0 = __builtin_amdgcn_mfma_f32_32x32x16_bf16(a0h, bl8[ks], ACC0, 0,0,0); \
    ACC1 = __builtin_amdgcn_mfma_f32_32x32x16_bf16(a1h, bl8[ks], ACC1, 0,0,0); \
  }

// ---------------- fused pre (grid-strided, double-buffered):
//   hout = x@Wpre ; xlr = x@Wcomb + bcat
// 12 waves: strips 0-3 -> Wpre cols (hout fp32), strips 4-11 -> Wcomb cols (xlr bf16)
__global__ __launch_bounds__(768) void pre_kernel(
    const float* __restrict__ A,
    const unsigned short* __restrict__ PhiF, const unsigned short* __restrict__ PloF,
    const unsigned short* __restrict__ ChiF, const unsigned short* __restrict__ CloF,
    const float* __restrict__ bcat,
    float* __restrict__ hout, unsigned short* __restrict__ xlr, int N, int ntiles)
{
  __shared__ short sh[2][16384];   // 2 x 32KB double buffer
  const int t = threadIdx.x;
  const int lane = t & 63, w = t >> 6;
  const int cl = lane & 31, kg = lane >> 5;
  const int sx = cl & 15;
  const int S = w * 32;
  const bool isP = S < 128;
  const int col = isP ? (S + cl) : (S - 128 + cl);
  const int NC  = isP ? 128 : 256;
  const unsigned short* Bhi = isP ? PhiF : ChiF;
  const unsigned short* Blo = isP ? PloF : CloF;
  const float bv = isP ? 0.f : bcat[col];

  // B-frags: loaded ONCE per block (coalesced frag-order)
  short8 bh[8], bl8[8];
  #pragma unroll
  for (int ks = 0; ks < 8; ++ks){
    size_t off = ((size_t)(ks*2 + kg)*NC + col)*8;
    bh[ks]  = *(const short8*)(Bhi + off);
    bl8[ks] = *(const short8*)(Blo + off);
  }

  // per-thread stage slots: g0 = t (all), g1 = t+768 (t<256 only)
  const int r_0 = t >> 4,         k8_0 = t & 15;
  const int g1  = t + 768;
  const int r_1 = g1 >> 4,        k8_1 = g1 & 15;
  const bool has1 = g1 < 1024;
  float4 pa0, pa1, pb0, pb1;

  auto LOAD = [&](int tl){
    int row0 = tl*64;
    int gr = row0 + r_0;
    if (gr < N){ const float* ap = A + (size_t)gr*128 + k8_0*8; pa0 = *(const float4*)ap; pa1 = *(const float4*)(ap+4); }
    else { pa0 = make_float4(0.f,0.f,0.f,0.f); pa1 = pa0; }
    if (has1){
      int gr1 = row0 + r_1;
      if (gr1 < N){ const float* ap = A + (size_t)gr1*128 + k8_1*8; pb0 = *(const float4*)ap; pb1 = *(const float4*)(ap+4); }
      else { pb0 = make_float4(0.f,0.f,0.f,0.f); pb1 = pb0; }
    }
  };
  auto STORE = [&](short* buf){
    {
      float vv[8] = {pa0.x,pa0.y,pa0.z,pa0.w,pa1.x,pa1.y,pa1.z,pa1.w};
      short8 hv, lv;
      #pragma unroll
      for (int j = 0; j < 8; ++j){
        unsigned short h = f2bf(vv[j]);
        hv[j] = (short)h;
        lv[j] = (short)f2bf(vv[j] - bf2f(h));
      }
      int slot = k8_0 ^ (r_0 & 15);
      *(short8*)&buf[r_0*128 + slot*8] = hv;
      *(short8*)&buf[8192 + r_0*128 + slot*8] = lv;
    }
    if (has1){
      float vv[8] = {pb0.x,pb0.y,pb0.z,pb0.w,pb1.x,pb1.y,pb1.z,pb1.w};
      short8 hv, lv;
      #pragma unroll
      for (int j = 0; j < 8; ++j){
        unsigned short h = f2bf(vv[j]);
        hv[j] = (short)h;
        lv[j] = (short)f2bf(vv[j] - bf2f(h));
      }
      int slot = k8_1 ^ (r_1 & 15);
      *(short8*)&buf[r_1*128 + slot*8] = hv;
      *(short8*)&buf[8192 + r_1*128 + slot*8] = lv;
    }
  };
  auto COMPUTE = [&](int tl, const short* alds){
    f32x16 acc0, acc1;
    #pragma unroll
    for (int i = 0; i < 16; ++i){ acc0[i] = 0.f; acc1[i] = 0.f; }
    const int r0 = cl;
    MFMA_KLOOP(acc0, acc1)
    int row0 = tl*64;
    if (isP){
      #pragma unroll
      for (int rt2 = 0; rt2 < 2; ++rt2){
        const f32x16& ac = rt2 ? acc1 : acc0;
        #pragma unroll
        for (int reg = 0; reg < 16; ++reg){
          int row = rt2*32 + (reg & 3) + 8*(reg >> 2) + 4*kg;
          int grow = row0 + row;
          if (grow < N) hout[(size_t)grow*128 + col] = ac[reg];
        }
      }
    } else {
      #pragma unroll
      for (int rt2 = 0; rt2 < 2; ++rt2){
        const f32x16& ac = rt2 ? acc1 : acc0;
        #pragma unroll
        for (int reg = 0; reg < 16; ++reg){
          int row = rt2*32 + (reg & 3) + 8*(reg >> 2) + 4*kg;
          int grow = row0 + row;
          if (grow < N) xlr[(size_t)grow*256 + col] = f2bf(ac[reg] + bv);
        }
      }
    }
  };

  int tile = blockIdx.x;
  if (tile >= ntiles) return;
  LOAD(tile);
  STORE(sh[0]);
  __syncthreads();
  int cur = 0;
  while (true){
    int next = tile + gridDim.x;
    bool more = next < ntiles;
    if (more) LOAD(next);          // HBM latency hides under MFMA below
    COMPUTE(tile, sh[cur]);
    if (!more) break;
    STORE(sh[cur^1]);
    __syncthreads();
    cur ^= 1;
    tile = next;
  }
}

// ---------------- fused MLP: logits = relu(h@W1+b1)@W2 + b2 ----------------
__global__ __launch_bounds__(256) void mlp_kernel(
    const float* __restrict__ A,
    const unsigned short* __restrict__ B1hi, const unsigned short* __restrict__ B1lo,
    const float* __restrict__ b1,
    const unsigned short* __restrict__ B2hi, const unsigned short* __restrict__ B2lo,
    const float* __restrict__ b2,
    float* __restrict__ logits, int N)
{
  __shared__ short alds[2*64*128];
  const int t = threadIdx.x;
  const int row0 = blockIdx.x * 64;
  stageA<256>(alds, A, row0, N, t);
  __syncthreads();

  const int lane = t & 63, w = t >> 6;
  const int cl = lane & 31, kg = lane >> 5;
  const int r0 = cl;
  const int sx = r0 & 15;

  {
    const int col = w*32 + cl;
    short8 bh[8], bl8[8];
    #pragma unroll
    for (int ks = 0; ks < 8; ++ks){
      size_t off = ((size_t)(ks*2 + kg)*128 + col)*8;   // frag-order, coalesced
      bh[ks]  = *(const short8*)(B1hi + off);
      bl8[ks] = *(const short8*)(B1lo + off);
    }
    f32x16 acc0, acc1;
    #pragma unroll
    for (int i = 0; i < 16; ++i){ acc0[i] = 0.f; acc1[i] = 0.f; }
    MFMA_KLOOP(acc0, acc1)

    float bv = b1[col];
    __syncthreads();
    #pragma unroll
    for (int rt = 0; rt < 2; ++rt){
      const f32x16& ac = rt ? acc1 : acc0;
      #pragma unroll
      for (int reg = 0; reg < 16; ++reg){
        int row = rt*32 + (reg & 3) + 8*(reg >> 2) + 4*kg;
        float v = fmaxf(ac[reg] + bv, 0.f);
        unsigned short h = f2bf(v);
        unsigned short l = f2bf(v - bf2f(h));
        int idx = row*128 + (((col >> 3) ^ (row & 15)) << 3) + (col & 7);
        alds[idx] = (short)h;
        alds[8192 + idx] = (short)l;
      }
    }
    __syncthreads();
  }

  if (w < 2){
    const int col = w*32 + cl;
    const bool cok = col < 40;
    short8 bh[8], bl8[8];
    #pragma unroll
    for (int ks = 0; ks < 8; ++ks){
      if (cok){
        size_t off = ((size_t)(ks*2 + kg)*40 + col)*8;  // frag-order, NC=40
        bh[ks]  = *(const short8*)(B2hi + off);
        bl8[ks] = *(const short8*)(B2lo + off);
      } else {
        #pragma unroll
        for (int j = 0; j < 8; ++j){ bh[ks][j] = 0; bl8[ks][j] = 0; }
      }
    }
    f32x16 acc0, acc1;
    #pragma unroll
    for (int i = 0; i < 16; ++i){ acc0[i] = 0.f; acc1[i] = 0.f; }
    MFMA_KLOOP(acc0, acc1)

    if (cok){
      float bv = b2[col];
      #pragma unroll
      for (int rt = 0; rt < 2; ++rt){
        const f32x16& ac = rt ? acc1 : acc0;
        #pragma unroll
        for (int reg = 0; reg < 16; ++reg){
          int row = rt*32 + (reg & 3) + 8*(reg >> 2) + 4*kg;
          int grow = row0 + row;
          if (grow < N) logits[(size_t)grow*40 + col] = ac[reg] + bv;
        }
      }
    }
  }
}

// ---------------- gather: 4 degree-matched nodes/wave, unroll-2 + depth-3 pipeline ----------------
__global__ __launch_bounds__(256) void gather_kernel(
    const int* __restrict__ rowptr, const int2* __restrict__ erec,
    const unsigned short* __restrict__ xlr,     // [N][256] bf16: xl | xr
    const int* __restrict__ perm,
    const float* __restrict__ We, const float* __restrict__ att,
    const float* __restrict__ msum, const float* __restrict__ bgat,
    float* __restrict__ hbuf, int N)
{
  const int wid  = threadIdx.x >> 6;
  const int lane = threadIdx.x & 63;
  const int g    = lane >> 4;
  const int l    = lane & 15;
  const int ch0  = l * 8;
  const int slot = (blockIdx.x*4 + wid)*4 + g;
  const bool nok = slot < N;
  const int n    = nok ? perm[slot] : 0;

  float xrv[8], wev[8], at6[8], at4[8];
  {
    short8 q = *(const short8*)&xlr[(size_t)n*256 + 128 + ch0];
    float4 w0 = *(const float4*)&We[ch0];
    float4 w1 = *(const float4*)&We[ch0+4];
    float4 a0 = *(const float4*)&att[ch0];
    float4 a1 = *(const float4*)&att[ch0+4];
    const float L2E = 1.4426950408889634f;
    float wv[8] = {w0.x,w0.y,w0.z,w0.w,w1.x,w1.y,w1.z,w1.w};
    float av[8] = {a0.x,a0.y,a0.z,a0.w,a1.x,a1.y,a1.z,a1.w};
    #pragma unroll
    for (int j = 0; j < 8; ++j){
      xrv[j] = bf2f((unsigned short)q[j]);
      wev[j] = wv[j];
      at6[j] = av[j]*0.6f*L2E;    // lrelu(z) = 0.6z + 0.4|z|, fold log2(e)
      at4[j] = av[j]*0.4f*L2E;
    }
  }

  float num[8];
  #pragma unroll
  for (int j = 0; j < 8; ++j) num[j] = 0.f;
  float den = 0.f;

  const float wm = msum[0];
  int beg = 0, end = 0;
  if (nok){ beg = rowptr[n]; end = rowptr[n + 1]; }
  const int cnt = nok ? (end - beg + 1) : 0;

  int itMax = cnt;
  itMax = max(itMax, __shfl_xor(itMax, 16, 64));
  itMax = max(itMax, __shfl_xor(itMax, 32, 64));

  const int2 selfrec = make_int2(n, __float_as_int(wm));

  int pos = beg;
  int2 rec0 = (pos     < end) ? erec[pos]     : selfrec;
  int2 rec1 = (pos + 1 < end) ? erec[pos + 1] : selfrec;
  int2 rec2 = (pos + 2 < end) ? erec[pos + 2] : selfrec;
  short8 pv0 = *(const short8*)&xlr[(size_t)rec0.x*256 + ch0];
  short8 pv1 = *(const short8*)&xlr[(size_t)rec1.x*256 + ch0];
  short8 pv2 = *(const short8*)&xlr[(size_t)rec2.x*256 + ch0];

  for (int it = 0; it < itMax; it += 2){
    int2 rec3 = (pos + 3 < end) ? erec[pos + 3] : selfrec;
    int2 rec4 = (pos + 4 < end) ? erec[pos + 4] : selfrec;
    short8 pv3 = *(const short8*)&xlr[(size_t)rec3.x*256 + ch0];
    short8 pv4 = *(const short8*)&xlr[(size_t)rec4.x*256 + ch0];

    {
      const bool act = it < cnt;
      const float wj = __int_as_float(rec0.y);
      float xlv[8];
      #pragma unroll
      for (int q = 0; q < 8; ++q) xlv[q] = bf2f((unsigned short)pv0[q]);
      float p = 0.f;
      #pragma unroll
      for (int q = 0; q < 8; ++q){
        float z = fmaf(wj, wev[q], xlv[q] + xrv[q]);
        p = fmaf(at6[q], z, p);
        p = fmaf(at4[q], fabsf(z), p);
      }
      p += __shfl_xor(p, 1, 64);
      p += __shfl_xor(p, 2, 64);
      float ex = act ? EXP2(p) : 0.f;
      den += ex;
      #pragma unroll
      for (int q = 0; q < 8; ++q) num[q] = fmaf(ex, xlv[q], num[q]);
    }
    {
      const bool act = (it + 1) < cnt;
      const float wj = __int_as_float(rec1.y);
      float xlv[8];
      #pragma unroll
      for (int q = 0; q < 8; ++q) xlv[q] = bf2f((unsigned short)pv1[q]);
      float p = 0.f;
      #pragma unroll
      for (int q = 0; q < 8; ++q){
        float z = fmaf(wj, wev[q], xlv[q] + xrv[q]);
        p = fmaf(at6[q], z, p);
        p = fmaf(at4[q], fabsf(z), p);
      }
      p += __shfl_xor(p, 1, 64);
      p += __shfl_xor(p, 2, 64);
      float ex = act ? EXP2(p) : 0.f;
      den += ex;
      #pragma unroll
      for (int q = 0; q < 8; ++q) num[q] = fmaf(ex, xlv[q], num[q]);
    }

    rec0 = rec2; rec1 = rec3; rec2 = rec4;
    pv0 = pv2;  pv1 = pv3;  pv2 = pv4;
    pos += 2;
  }

  if (nok){
    float inv = 1.f / (den + 1e-16f);
    float o[8];
    #pragma unroll
    for (int j = 0; j < 8; ++j){
      float v = num[j]*inv + bgat[ch0+j];
      o[j] = v > 0.f ? v : expm1f(v);   // ELU
    }
    float4 h0a = *(const float4*)&hbuf[(size_t)n*128 + ch0];
    float4 h0b = *(const float4*)&hbuf[(size_t)n*128 + ch0 + 4];
    h0a.x += o[0]; h0a.y += o[1]; h0a.z += o[2]; h0a.w += o[3];
    h0b.x += o[4]; h0b.y += o[5]; h0b.z += o[6]; h0b.w += o[7];
    *(float4*)&hbuf[(size_t)n*128 + ch0]     = h0a;
    *(float4*)&hbuf[(size_t)n*128 + ch0 + 4] = h0b;
  }
}

extern "C" void kernel_launch(void* const* d_in, const int* in_sizes, int n_in,
                              void* d_out, int out_size, void* d_ws, size_t ws_size,
                              hipStream_t stream)
{
  const float* x    = (const float*)d_in[0];
  const int*   ei   = (const int*)  d_in[1];
  const float* ew   = (const float*)d_in[2];
  const float* Wpre = (const float*)d_in[3];
  const float* Wl   = (const float*)d_in[4];
  const float* bl   = (const float*)d_in[5];
  const float* Wr   = (const float*)d_in[6];
  const float* br   = (const float*)d_in[7];
  const float* We   = (const float*)d_in[8];
  const float* att  = (const float*)d_in[9];
  const float* bgat = (const float*)d_in[10];
  const float* W1   = (const float*)d_in[11];
  const float* b1   = (const float*)d_in[12];
  const float* W2   = (const float*)d_in[13];
  const float* b2   = (const float*)d_in[14];

  const int N = in_sizes[0] / 128;
  const int E = in_sizes[2];
  const int nb = (N + 255) / 256;

  float* hout   = (float*)d_out;               // [N,128]
  float* logits = hout + (size_t)N*128;        // [N,40]

  // workspace layout
  unsigned short* xlr = (unsigned short*)d_ws; // N*256 bf16 (xl | xr per row)
  int2*  erec   = (int2*)(xlr + (size_t)N*256);// E records (src, w)
  int*   rk     = (int*)(erec + E);            // E ranks
  int*   rowptr = rk + E;                      // N+1
  int*   cursor = rowptr + N + 1;              // N (deg)
  float* msum   = (float*)(cursor + N);        // 1
  int*   dhist  = (int*)(msum + 1);            // 256
  int*   bsum   = dhist + 256;                 // nb
  int*   boff   = bsum + nb;                   // nb
  int*   dhoff  = boff + nb;                   // 256
  int*   perm   = dhoff + 256;                 // N
  float* bcat   = (float*)(perm + N);          // 256
  unsigned short* wsp = (unsigned short*)(((uintptr_t)(bcat + 256) + 15) & ~(uintptr_t)15);
  unsigned short* PhiF  = wsp;                 // 128*128
  unsigned short* PloF  = PhiF + 16384;
  unsigned short* ChiF  = PloF + 16384;        // 256*128 (Wcomb)
  unsigned short* CloF  = ChiF + 32768;
  unsigned short* W1hiF = CloF + 32768;        // 128*128
  unsigned short* W1loF = W1hiF + 16384;
  unsigned short* W2hiF = W1loF + 16384;       // 40*128
  unsigned short* W2loF = W2hiF + 5120;

  hipMemsetAsync(cursor, 0, (size_t)(N + 1 + 256) * sizeof(int), stream);

  wprep<<<150, 256, 0, stream>>>(Wpre, W1, W2, bl, br,
                                 PhiF, PloF, W1hiF, W1loF, W2hiF, W2loF, bcat);
  wcomb_kernel<<<128, 256, 0, stream>>>(Wpre, Wl, Wr, ChiF, CloF);
  count_mean<<<1024, 256, 0, stream>>>(ei, ew, cursor, rk, msum, E);
  scan1_kernel<<<nb, 256, 0, stream>>>(cursor, rowptr, bsum, dhist, N);
  scan2_kernel<<<1, 512, 0, stream>>>(bsum, boff, nb, dhist, dhoff);
  scan3_kernel<<<nb, 256, 0, stream>>>(rowptr, boff, cursor, dhoff, perm, N);
  fill_kernel<<<(E + 255)/256, 256, 0, stream>>>(ei, ew, rowptr, rk, erec, E);

  const int ntiles = (N + 63) / 64;
  pre_kernel<<<512, 768, 0, stream>>>(x, PhiF, PloF, ChiF, CloF, bcat, hout, xlr, N, ntiles);

  gather_kernel<<<(N + 15)/16, 256, 0, stream>>>(rowptr, erec, xlr, perm, We, att, msum, bgat, hout, N);

  mlp_kernel<<<(N + 63)/64, 256, 0, stream>>>(hout, W1hiF, W1loF, b1, W2hiF, W2loF, b2, logits, N);
}

// Round 17
// 294.708 us; speedup vs baseline: 1.0837x; 1.0155x over previous
//
#include <hip/hip_runtime.h>

typedef __attribute__((ext_vector_type(8))) short short8;
typedef __attribute__((ext_vector_type(16))) float f32x16;

#if __has_builtin(__builtin_amdgcn_exp2f)
#define EXP2(x) __builtin_amdgcn_exp2f(x)
#else
#define EXP2(x) exp2f(x)
#endif

static __device__ __forceinline__ unsigned short f2bf(float f){
  unsigned u = __float_as_uint(f);
  unsigned r = u + 0x7fffu + ((u >> 16) & 1u);
  return (unsigned short)(r >> 16);
}
static __device__ __forceinline__ float bf2f(unsigned short h){
  return __uint_as_float(((unsigned)h) << 16);
}

// ---------------- merged weight prep (wprep + wcomb in one launch) ----------------
__global__ __launch_bounds__(256) void wprep(
    const float* __restrict__ Wpre, const float* __restrict__ Wl,
    const float* __restrict__ Wr, const float* __restrict__ W1,
    const float* __restrict__ W2, const float* __restrict__ bl,
    const float* __restrict__ br,
    unsigned short* __restrict__ PhiF, unsigned short* __restrict__ PloF,
    unsigned short* __restrict__ ChiF, unsigned short* __restrict__ CloF,
    unsigned short* __restrict__ W1hiF, unsigned short* __restrict__ W1loF,
    unsigned short* __restrict__ W2hiF, unsigned short* __restrict__ W2loF,
    float* __restrict__ bcat){
  if (blockIdx.x < 150){
    int i = blockIdx.x*256 + threadIdx.x;
    float v; unsigned short* hp; unsigned short* lp; size_t idx;
    if (i < 16384){
      int k = i >> 7, c = i & 127;
      v = Wpre[i]; hp = PhiF; lp = PloF;
      idx = ((size_t)(k>>3)*128 + c)*8 + (k&7);
    } else if (i < 32768){
      int j = i - 16384; int k = j >> 7, c = j & 127;
      v = W1[j]; hp = W1hiF; lp = W1loF;
      idx = ((size_t)(k>>3)*128 + c)*8 + (k&7);
    } else if (i < 37888){
      int j = i - 32768; int k = j / 40, c = j % 40;
      v = W2[j]; hp = W2hiF; lp = W2loF;
      idx = ((size_t)(k>>3)*40 + c)*8 + (k&7);
    } else if (i < 38144){
      int j = i - 37888;
      bcat[j] = (j < 128) ? bl[j] : br[j-128];
      return;
    } else return;
    unsigned short h = f2bf(v);
    hp[idx] = h;
    lp[idx] = f2bf(v - bf2f(h));
  } else {
    int tid = (blockIdx.x - 150)*256 + threadIdx.x;   // 32768 = 128 x 256
    int r = tid >> 8;
    int c = tid & 255;
    const float* B = (c < 128) ? (Wl + c) : (Wr + (c - 128));
    float s = 0.f;
    for (int k = 0; k < 128; ++k)
      s = fmaf(Wpre[r*128 + k], B[(size_t)k*128], s);
    unsigned short h = f2bf(s);
    size_t idx = ((size_t)(r>>3)*256 + c)*8 + (r&7);
    ChiF[idx] = h;
    CloF[idx] = f2bf(s - bf2f(h));
  }
}

// ---------------- histogram + rank + mean in one pass ----------------
__global__ void count_mean(const int* __restrict__ ei, const float* __restrict__ ew,
                           int* __restrict__ deg, int* __restrict__ rk,
                           float* __restrict__ msum, int E){
  float s = 0.f;
  for (int e = blockIdx.x*256 + threadIdx.x; e < E; e += gridDim.x*256){
    rk[e] = atomicAdd(&deg[ei[E + e]], 1);
    s += ew[e];
  }
  for (int d = 32; d > 0; d >>= 1) s += __shfl_down(s, d, 64);
  __shared__ float ps[4];
  int lane = threadIdx.x & 63, w = threadIdx.x >> 6;
  if (lane == 0) ps[w] = s;
  __syncthreads();
  if (threadIdx.x == 0) atomicAdd(msum, (ps[0]+ps[1]+ps[2]+ps[3]) / (float)E);
}

// ---------------- scans (+ LDS-aggregated degree histogram / perm) ----------------
__global__ __launch_bounds__(256) void scan1_kernel(const int* __restrict__ deg, int* __restrict__ rowptr,
                                                    int* __restrict__ bsum, int* __restrict__ dhist, int N){
  __shared__ int s[256];
  __shared__ int lhist[256];
  int i = blockIdx.x*256 + threadIdx.x;
  lhist[threadIdx.x] = 0;
  __syncthreads();
  int v = (i < N) ? deg[i] : 0;
  if (i < N) atomicAdd(&lhist[v < 255 ? v : 255], 1);
  s[threadIdx.x] = v;
  __syncthreads();
  for (int off = 1; off < 256; off <<= 1){
    int t = (threadIdx.x >= off) ? s[threadIdx.x - off] : 0;
    __syncthreads();
    s[threadIdx.x] += t;
    __syncthreads();
  }
  if (i < N) rowptr[i + 1] = s[threadIdx.x];
  if (threadIdx.x == 255) bsum[blockIdx.x] = s[255];
  int c = lhist[threadIdx.x];
  if (c > 0) atomicAdd(&dhist[threadIdx.x], c);
}

__global__ __launch_bounds__(512) void scan2_kernel(const int* __restrict__ bsum, int* __restrict__ boff, int nb,
                                                    const int* __restrict__ dhist, int* __restrict__ dhoff){
  __shared__ int s[512];
  __shared__ int s2[256];
  int v = (threadIdx.x < nb) ? bsum[threadIdx.x] : 0;
  s[threadIdx.x] = v;
  __syncthreads();
  for (int off = 1; off < 512; off <<= 1){
    int t = (threadIdx.x >= off) ? s[threadIdx.x - off] : 0;
    __syncthreads();
    s[threadIdx.x] += t;
    __syncthreads();
  }
  if (threadIdx.x < nb) boff[threadIdx.x] = s[threadIdx.x] - v;
  int v2 = 0;
  if (threadIdx.x < 256){ v2 = dhist[threadIdx.x]; s2[threadIdx.x] = v2; }
  __syncthreads();
  for (int off = 1; off < 256; off <<= 1){
    int t = 0;
    if (threadIdx.x < 256 && threadIdx.x >= off) t = s2[threadIdx.x - off];
    __syncthreads();
    if (threadIdx.x < 256) s2[threadIdx.x] += t;
    __syncthreads();
  }
  if (threadIdx.x < 256) dhoff[threadIdx.x] = s2[threadIdx.x] - v2;
}

__global__ __launch_bounds__(256) void scan3_kernel(int* __restrict__ rowptr, const int* __restrict__ boff,
                                                    const int* __restrict__ deg, int* __restrict__ dhoff,
                                                    int* __restrict__ perm, int N){
  __shared__ int lcnt[256];
  __shared__ int lbase[256];
  int i = blockIdx.x*256 + threadIdx.x;
  lcnt[threadIdx.x] = 0;
  __syncthreads();
  if (i == 0) rowptr[0] = 0;
  int d = 0, lr = 0;
  if (i < N){
    rowptr[i + 1] += boff[i >> 8];
    d = deg[i]; d = d < 255 ? d : 255;
    lr = atomicAdd(&lcnt[d], 1);
  }
  __syncthreads();
  int c = lcnt[threadIdx.x];
  if (c > 0) lbase[threadIdx.x] = atomicAdd(&dhoff[threadIdx.x], c);
  __syncthreads();
  if (i < N) perm[lbase[d] + lr] = i;
}

// rank-based scatter: no atomics
__global__ void fill_kernel(const int* __restrict__ ei, const float* __restrict__ ew,
                            const int* __restrict__ rowptr, const int* __restrict__ rk,
                            int2* __restrict__ erec, int E){
  int e = blockIdx.x*256 + threadIdx.x;
  if (e >= E) return;
  int dst = ei[E + e];
  erec[rowptr[dst] + rk[e]] = make_int2(ei[e], __float_as_int(ew[e]));
}

// ---------------- stage A tile (64x128 fp32 -> split bf16 LDS) ----------------
template<int NT>
static __device__ __forceinline__ void stageA(short* alds, const float* __restrict__ A,
                                              int row0, int N, int t){
  for (int g = t; g < 1024; g += NT){
    int r = g >> 4, k8 = g & 15;
    int grow = row0 + r;
    float4 p0, p1;
    if (grow < N){
      const float* ap = A + (size_t)grow*128 + k8*8;
      p0 = *(const float4*)ap;
      p1 = *(const float4*)(ap + 4);
    } else {
      p0 = make_float4(0.f,0.f,0.f,0.f); p1 = p0;
    }
    float vv[8] = {p0.x,p0.y,p0.z,p0.w,p1.x,p1.y,p1.z,p1.w};
    short8 hv, lv;
    #pragma unroll
    for (int j = 0; j < 8; ++j){
      unsigned short h = f2bf(vv[j]);
      hv[j] = (short)h;
      lv[j] = (short)f2bf(vv[j] - bf2f(h));
    }
    int slot = k8 ^ (r & 15);
    *(short8*)&alds[r*128 + slot*8] = hv;
    *(short8*)&alds[8192 + r*128 + slot*8] = lv;
  }
}

// 3-pass MFMA over two 32-row tiles, A from LDS, B frags (BH/BL register arrays)
#define MFMA_KLOOP(ACC0, ACC1, BH, BL) \
  _Pragma("unroll") \
  for (int ks = 0; ks < 8; ++ks){ \
    int k8 = ks*2 + kg; \
    const short* a0 = &alds[r0*128 + (k8 ^ sx)*8]; \
    const short* a1 = &alds[(r0+32)*128 + (k8 ^ sx)*8]; \
    short8 a0h = *(const short8*)a0; \
    short8 a0l = *(const short8*)(a0 + 8192); \
    short8 a1h = *(const short8*)a1; \
    short8 a1l = *(const short8*)(a1 + 8192); \
    ACC0 = __builtin_amdgcn_mfma_f32_32x32x16_bf16(a0h, BH[ks], ACC0, 0,0,0); \
    ACC1 = __builtin_amdgcn_mfma_f32_32x32x16_bf16(a1h, BH[ks], ACC1, 0,0,0); \
    ACC0 = __builtin_amdgcn_mfma_f32_32x32x16_bf16(a0l, BH[ks], ACC0, 0,0,0); \
    ACC1 = __builtin_amdgcn_mfma_f32_32x32x16_bf16(a1l, BH[ks], ACC1, 0,0,0); \
    ACC0 = __builtin_amdgcn_mfma_f32_32x32x16_bf16(a0h, BL[ks], ACC0, 0,0,0); \
    ACC1 = __builtin_amdgcn_mfma_f32_32x32x16_bf16(a1h, BL[ks], ACC1, 0,0,0); \
  }

// ---------------- fused pre (grid-strided, double-buffered) ----------------
__global__ __launch_bounds__(768) void pre_kernel(
    const float* __restrict__ A,
    const unsigned short* __restrict__ PhiF, const unsigned short* __restrict__ PloF,
    const unsigned short* __restrict__ ChiF, const unsigned short* __restrict__ CloF,
    const float* __restrict__ bcat,
    float* __restrict__ hout, unsigned short* __restrict__ xlr, int N, int ntiles)
{
  __shared__ short sh[2][16384];
  const int t = threadIdx.x;
  const int lane = t & 63, w = t >> 6;
  const int cl = lane & 31, kg = lane >> 5;
  const int sx = cl & 15;
  const int S = w * 32;
  const bool isP = S < 128;
  const int col = isP ? (S + cl) : (S - 128 + cl);
  const int NC  = isP ? 128 : 256;
  const unsigned short* Bhi = isP ? PhiF : ChiF;
  const unsigned short* Blo = isP ? PloF : CloF;
  const float bv = isP ? 0.f : bcat[col];

  short8 bh[8], bl8[8];
  #pragma unroll
  for (int ks = 0; ks < 8; ++ks){
    size_t off = ((size_t)(ks*2 + kg)*NC + col)*8;
    bh[ks]  = *(const short8*)(Bhi + off);
    bl8[ks] = *(const short8*)(Blo + off);
  }

  const int r_0 = t >> 4,  k8_0 = t & 15;
  const int g1  = t + 768;
  const int r_1 = g1 >> 4, k8_1 = g1 & 15;
  const bool has1 = g1 < 1024;
  float4 pa0, pa1, pb0, pb1;

  auto LOAD = [&](int tl){
    int row0 = tl*64;
    int gr = row0 + r_0;
    if (gr < N){ const float* ap = A + (size_t)gr*128 + k8_0*8; pa0 = *(const float4*)ap; pa1 = *(const float4*)(ap+4); }
    else { pa0 = make_float4(0.f,0.f,0.f,0.f); pa1 = pa0; }
    if (has1){
      int gr1 = row0 + r_1;
      if (gr1 < N){ const float* ap = A + (size_t)gr1*128 + k8_1*8; pb0 = *(const float4*)ap; pb1 = *(const float4*)(ap+4); }
      else { pb0 = make_float4(0.f,0.f,0.f,0.f); pb1 = pb0; }
    }
  };
  auto STORE = [&](short* buf){
    {
      float vv[8] = {pa0.x,pa0.y,pa0.z,pa0.w,pa1.x,pa1.y,pa1.z,pa1.w};
      short8 hv, lv;
      #pragma unroll
      for (int j = 0; j < 8; ++j){
        unsigned short h = f2bf(vv[j]);
        hv[j] = (short)h;
        lv[j] = (short)f2bf(vv[j] - bf2f(h));
      }
      int slot = k8_0 ^ (r_0 & 15);
      *(short8*)&buf[r_0*128 + slot*8] = hv;
      *(short8*)&buf[8192 + r_0*128 + slot*8] = lv;
    }
    if (has1){
      float vv[8] = {pb0.x,pb0.y,pb0.z,pb0.w,pb1.x,pb1.y,pb1.z,pb1.w};
      short8 hv, lv;
      #pragma unroll
      for (int j = 0; j < 8; ++j){
        unsigned short h = f2bf(vv[j]);
        hv[j] = (short)h;
        lv[j] = (short)f2bf(vv[j] - bf2f(h));
      }
      int slot = k8_1 ^ (r_1 & 15);
      *(short8*)&buf[r_1*128 + slot*8] = hv;
      *(short8*)&buf[8192 + r_1*128 + slot*8] = lv;
    }
  };
  auto COMPUTE = [&](int tl, const short* alds){
    f32x16 acc0, acc1;
    #pragma unroll
    for (int i = 0; i < 16; ++i){ acc0[i] = 0.f; acc1[i] = 0.f; }
    const int r0 = cl;
    MFMA_KLOOP(acc0, acc1, bh, bl8)
    int row0 = tl*64;
    if (isP){
      #pragma unroll
      for (int rt2 = 0; rt2 < 2; ++rt2){
        const f32x16& ac = rt2 ? acc1 : acc0;
        #pragma unroll
        for (int reg = 0; reg < 16; ++reg){
          int row = rt2*32 + (reg & 3) + 8*(reg >> 2) + 4*kg;
          int grow = row0 + row;
          if (grow < N) hout[(size_t)grow*128 + col] = ac[reg];
        }
      }
    } else {
      #pragma unroll
      for (int rt2 = 0; rt2 < 2; ++rt2){
        const f32x16& ac = rt2 ? acc1 : acc0;
        #pragma unroll
        for (int reg = 0; reg < 16; ++reg){
          int row = rt2*32 + (reg & 3) + 8*(reg >> 2) + 4*kg;
          int grow = row0 + row;
          if (grow < N) xlr[(size_t)grow*256 + col] = f2bf(ac[reg] + bv);
        }
      }
    }
  };

  int tile = blockIdx.x;
  if (tile >= ntiles) return;
  LOAD(tile);
  STORE(sh[0]);
  __syncthreads();
  int cur = 0;
  while (true){
    int next = tile + gridDim.x;
    bool more = next < ntiles;
    if (more) LOAD(next);
    COMPUTE(tile, sh[cur]);
    if (!more) break;
    STORE(sh[cur^1]);
    __syncthreads();
    cur ^= 1;
    tile = next;
  }
}

// ---------------- fused MLP (grid-strided, single buffer) ----------------
// FIX: phase-2 MFMA runs with FULL waves 0/1 (zero-filled frags for col>=40);
// MFMA sources operands from all 64 lanes regardless of exec mask.
__global__ __launch_bounds__(256) void mlp_kernel(
    const float* __restrict__ A,
    const unsigned short* __restrict__ B1hi, const unsigned short* __restrict__ B1lo,
    const float* __restrict__ b1,
    const unsigned short* __restrict__ B2hi, const unsigned short* __restrict__ B2lo,
    const float* __restrict__ b2,
    float* __restrict__ logits, int N, int ntiles)
{
  __shared__ short alds[2*64*128];
  const int t = threadIdx.x;
  const int lane = t & 63, w = t >> 6;
  const int cl = lane & 31, kg = lane >> 5;
  const int sx = cl & 15;
  const int col = w*32 + cl;

  // hoisted W1 frags + bias
  short8 b1h[8], b1l[8];
  #pragma unroll
  for (int ks = 0; ks < 8; ++ks){
    size_t off = ((size_t)(ks*2 + kg)*128 + col)*8;
    b1h[ks] = *(const short8*)(B1hi + off);
    b1l[ks] = *(const short8*)(B1lo + off);
  }
  const float bv1 = b1[col];

  // hoisted W2 frags: zero-filled for lanes with col >= 40 (full-wave MFMA safety)
  const bool cok = (w < 2) && (col < 40);
  short8 b2h[8], b2l[8];
  #pragma unroll
  for (int ks = 0; ks < 8; ++ks){
    if (cok){
      size_t off = ((size_t)(ks*2 + kg)*40 + col)*8;
      b2h[ks] = *(const short8*)(B2hi + off);
      b2l[ks] = *(const short8*)(B2lo + off);
    } else {
      #pragma unroll
      for (int j = 0; j < 8; ++j){ b2h[ks][j] = 0; b2l[ks][j] = 0; }
    }
  }
  const float bv2 = cok ? b2[col] : 0.f;

  for (int tile = blockIdx.x; tile < ntiles; tile += gridDim.x){
    __syncthreads();                    // prior iteration's phase-2 readers done
    stageA<256>(alds, A, tile*64, N, t);
    __syncthreads();

    // ---- phase 1: relu(h@W1+b1) -> alds ----
    {
      f32x16 acc0, acc1;
      #pragma unroll
      for (int i = 0; i < 16; ++i){ acc0[i] = 0.f; acc1[i] = 0.f; }
      const int r0 = cl;
      MFMA_KLOOP(acc0, acc1, b1h, b1l)
      __syncthreads();                  // all h reads done before overwrite
      #pragma unroll
      for (int rt = 0; rt < 2; ++rt){
        const f32x16& ac = rt ? acc1 : acc0;
        #pragma unroll
        for (int reg = 0; reg < 16; ++reg){
          int row = rt*32 + (reg & 3) + 8*(reg >> 2) + 4*kg;
          float v = fmaxf(ac[reg] + bv1, 0.f);
          unsigned short h = f2bf(v);
          unsigned short l = f2bf(v - bf2f(h));
          int idx = row*128 + (((col >> 3) ^ (row & 15)) << 3) + (col & 7);
          alds[idx] = (short)h;
          alds[8192 + idx] = (short)l;
        }
      }
      __syncthreads();
    }

    // ---- phase 2: logits — FULL waves 0/1 execute the MFMA ----
    if (w < 2){
      f32x16 acc0, acc1;
      #pragma unroll
      for (int i = 0; i < 16; ++i){ acc0[i] = 0.f; acc1[i] = 0.f; }
      const int r0 = cl;
      MFMA_KLOOP(acc0, acc1, b2h, b2l)
      if (cok){
        int row0 = tile*64;
        #pragma unroll
        for (int rt = 0; rt < 2; ++rt){
          const f32x16& ac = rt ? acc1 : acc0;
          #pragma unroll
          for (int reg = 0; reg < 16; ++reg){
            int row = rt*32 + (reg & 3) + 8*(reg >> 2) + 4*kg;
            int grow = row0 + row;
            if (grow < N) logits[(size_t)grow*40 + col] = ac[reg] + bv2;
          }
        }
      }
    }
  }
}

// ---------------- gather: 4 degree-matched nodes/wave, LPT order, depth-3 pipeline ----------------
__global__ __launch_bounds__(256) void gather_kernel(
    const int* __restrict__ rowptr, const int2* __restrict__ erec,
    const unsigned short* __restrict__ xlr,     // [N][256] bf16: xl | xr
    const int* __restrict__ perm,
    const float* __restrict__ We, const float* __restrict__ att,
    const float* __restrict__ msum, const float* __restrict__ bgat,
    float* __restrict__ hbuf, int N)
{
  const int wid  = threadIdx.x >> 6;
  const int lane = threadIdx.x & 63;
  const int g    = lane >> 4;
  const int l    = lane & 15;
  const int ch0  = l * 8;
  const int slot = (blockIdx.x*4 + wid)*4 + g;
  const bool nok = slot < N;
  const int n    = nok ? perm[N-1-slot] : 0;   // LPT: high-degree nodes first

  float xrv[8], wev[8], at6[8], at4[8];
  {
    short8 q = *(const short8*)&xlr[(size_t)n*256 + 128 + ch0];
    float4 w0 = *(const float4*)&We[ch0];
    float4 w1 = *(const float4*)&We[ch0+4];
    float4 a0 = *(const float4*)&att[ch0];
    float4 a1 = *(const float4*)&att[ch0+4];
    const float L2E = 1.4426950408889634f;
    float wv[8] = {w0.x,w0.y,w0.z,w0.w,w1.x,w1.y,w1.z,w1.w};
    float av[8] = {a0.x,a0.y,a0.z,a0.w,a1.x,a1.y,a1.z,a1.w};
    #pragma unroll
    for (int j = 0; j < 8; ++j){
      xrv[j] = bf2f((unsigned short)q[j]);
      wev[j] = wv[j];
      at6[j] = av[j]*0.6f*L2E;    // lrelu(z) = 0.6z + 0.4|z|, fold log2(e)
      at4[j] = av[j]*0.4f*L2E;
    }
  }

  float num[8];
  #pragma unroll
  for (int j = 0; j < 8; ++j) num[j] = 0.f;
  float den = 0.f;

  const float wm = msum[0];
  int beg = 0, end = 0;
  if (nok){ beg = rowptr[n]; end = rowptr[n + 1]; }
  const int cnt = nok ? (end - beg + 1) : 0;

  int itMax = cnt;
  itMax = max(itMax, __shfl_xor(itMax, 16, 64));
  itMax = max(itMax, __shfl_xor(itMax, 32, 64));

  const int2 selfrec = make_int2(n, __float_as_int(wm));

  int pos = beg;
  int2 rec0 = (pos     < end) ? erec[pos]     : selfrec;
  int2 rec1 = (pos + 1 < end) ? erec[pos + 1] : selfrec;
  int2 rec2 = (pos + 2 < end) ? erec[pos + 2] : selfrec;
  short8 pv0 = *(const short8*)&xlr[(size_t)rec0.x*256 + ch0];
  short8 pv1 = *(const short8*)&xlr[(size_t)rec1.x*256 + ch0];
  short8 pv2 = *(const short8*)&xlr[(size_t)rec2.x*256 + ch0];

  for (int it = 0; it < itMax; it += 2){
    int2 rec3 = (pos + 3 < end) ? erec[pos + 3] : selfrec;
    int2 rec4 = (pos + 4 < end) ? erec[pos + 4] : selfrec;
    short8 pv3 = *(const short8*)&xlr[(size_t)rec3.x*256 + ch0];
    short8 pv4 = *(const short8*)&xlr[(size_t)rec4.x*256 + ch0];

    {
      const bool act = it < cnt;
      const float wj = __int_as_float(rec0.y);
      float xlv[8];
      #pragma unroll
      for (int q = 0; q < 8; ++q) xlv[q] = bf2f((unsigned short)pv0[q]);
      float p = 0.f;
      #pragma unroll
      for (int q = 0; q < 8; ++q){
        float z = fmaf(wj, wev[q], xlv[q] + xrv[q]);
        p = fmaf(at6[q], z, p);
        p = fmaf(at4[q], fabsf(z), p);
      }
      p += __shfl_xor(p, 1, 64);
      p += __shfl_xor(p, 2, 64);
      float ex = act ? EXP2(p) : 0.f;
      den += ex;
      #pragma unroll
      for (int q = 0; q < 8; ++q) num[q] = fmaf(ex, xlv[q], num[q]);
    }
    {
      const bool act = (it + 1) < cnt;
      const float wj = __int_as_float(rec1.y);
      float xlv[8];
      #pragma unroll
      for (int q = 0; q < 8; ++q) xlv[q] = bf2f((unsigned short)pv1[q]);
      float p = 0.f;
      #pragma unroll
      for (int q = 0; q < 8; ++q){
        float z = fmaf(wj, wev[q], xlv[q] + xrv[q]);
        p = fmaf(at6[q], z, p);
        p = fmaf(at4[q], fabsf(z), p);
      }
      p += __shfl_xor(p, 1, 64);
      p += __shfl_xor(p, 2, 64);
      float ex = act ? EXP2(p) : 0.f;
      den += ex;
      #pragma unroll
      for (int q = 0; q < 8; ++q) num[q] = fmaf(ex, xlv[q], num[q]);
    }

    rec0 = rec2; rec1 = rec3; rec2 = rec4;
    pv0 = pv2;  pv1 = pv3;  pv2 = pv4;
    pos += 2;
  }

  if (nok){
    float inv = 1.f / (den + 1e-16f);
    float o[8];
    #pragma unroll
    for (int j = 0; j < 8; ++j){
      float v = num[j]*inv + bgat[ch0+j];
      o[j] = v > 0.f ? v : expm1f(v);   // ELU
    }
    float4 h0a = *(const float4*)&hbuf[(size_t)n*128 + ch0];
    float4 h0b = *(const float4*)&hbuf[(size_t)n*128 + ch0 + 4];
    h0a.x += o[0]; h0a.y += o[1]; h0a.z += o[2]; h0a.w += o[3];
    h0b.x += o[4]; h0b.y += o[5]; h0b.z += o[6]; h0b.w += o[7];
    *(float4*)&hbuf[(size_t)n*128 + ch0]     = h0a;
    *(float4*)&hbuf[(size_t)n*128 + ch0 + 4] = h0b;
  }
}

extern "C" void kernel_launch(void* const* d_in, const int* in_sizes, int n_in,
                              void* d_out, int out_size, void* d_ws, size_t ws_size,
                              hipStream_t stream)
{
  const float* x    = (const float*)d_in[0];
  const int*   ei   = (const int*)  d_in[1];
  const float* ew   = (const float*)d_in[2];
  const float* Wpre = (const float*)d_in[3];
  const float* Wl   = (const float*)d_in[4];
  const float* bl   = (const float*)d_in[5];
  const float* Wr   = (const float*)d_in[6];
  const float* br   = (const float*)d_in[7];
  const float* We   = (const float*)d_in[8];
  const float* att  = (const float*)d_in[9];
  const float* bgat = (const float*)d_in[10];
  const float* W1   = (const float*)d_in[11];
  const float* b1   = (const float*)d_in[12];
  const float* W2   = (const float*)d_in[13];
  const float* b2   = (const float*)d_in[14];

  const int N = in_sizes[0] / 128;
  const int E = in_sizes[2];
  const int nb = (N + 255) / 256;

  float* hout   = (float*)d_out;               // [N,128]
  float* logits = hout + (size_t)N*128;        // [N,40]

  // workspace layout
  unsigned short* xlr = (unsigned short*)d_ws; // N*256 bf16 (xl | xr per row)
  int2*  erec   = (int2*)(xlr + (size_t)N*256);// E records (src, w)
  int*   rk     = (int*)(erec + E);            // E ranks
  int*   rowptr = rk + E;                      // N+1
  int*   cursor = rowptr + N + 1;              // N (deg)
  float* msum   = (float*)(cursor + N);        // 1
  int*   dhist  = (int*)(msum + 1);            // 256
  int*   bsum   = dhist + 256;                 // nb
  int*   boff   = bsum + nb;                   // nb
  int*   dhoff  = boff + nb;                   // 256
  int*   perm   = dhoff + 256;                 // N
  float* bcat   = (float*)(perm + N);          // 256
  unsigned short* wsp = (unsigned short*)(((uintptr_t)(bcat + 256) + 15) & ~(uintptr_t)15);
  unsigned short* PhiF  = wsp;                 // 128*128
  unsigned short* PloF  = PhiF + 16384;
  unsigned short* ChiF  = PloF + 16384;        // 256*128 (Wcomb)
  unsigned short* CloF  = ChiF + 32768;
  unsigned short* W1hiF = CloF + 32768;        // 128*128
  unsigned short* W1loF = W1hiF + 16384;
  unsigned short* W2hiF = W1loF + 16384;       // 40*128
  unsigned short* W2loF = W2hiF + 5120;

  hipMemsetAsync(cursor, 0, (size_t)(N + 1 + 256) * sizeof(int), stream);

  wprep<<<278, 256, 0, stream>>>(Wpre, Wl, Wr, W1, W2, bl, br,
                                 PhiF, PloF, ChiF, CloF, W1hiF, W1loF, W2hiF, W2loF, bcat);
  count_mean<<<1024, 256, 0, stream>>>(ei, ew, cursor, rk, msum, E);
  scan1_kernel<<<nb, 256, 0, stream>>>(cursor, rowptr, bsum, dhist, N);
  scan2_kernel<<<1, 512, 0, stream>>>(bsum, boff, nb, dhist, dhoff);
  scan3_kernel<<<nb, 256, 0, stream>>>(rowptr, boff, cursor, dhoff, perm, N);
  fill_kernel<<<(E + 255)/256, 256, 0, stream>>>(ei, ew, rowptr, rk, erec, E);

  const int ntiles = (N + 63) / 64;
  pre_kernel<<<512, 768, 0, stream>>>(x, PhiF, PloF, ChiF, CloF, bcat, hout, xlr, N, ntiles);

  gather_kernel<<<(N + 15)/16, 256, 0, stream>>>(rowptr, erec, xlr, perm, We, att, msum, bgat, hout, N);

  mlp_kernel<<<512, 256, 0, stream>>>(hout, W1hiF, W1loF, b1, W2hiF, W2loF, b2, logits, N, ntiles);
}